// Round 7
// baseline (193.344 us; speedup 1.0000x reference)
//
#include <hip/hip_runtime.h>
#include <math.h>

// Problem constants (match reference)
#define NB 16       // batch
#define NL 512      // rows per batch
#define NS 512      // samples per row
#define NE 3000     // ecdf grid points (3*N_REF)
#define NR 1000     // ref points
#define NROWS (NB * NL)
#define NBIN 512    // counting-sort bins (avg 1 sample/bin)

__device__ __forceinline__ float fast_rcp(float x) { return __builtin_amdgcn_rcpf(x); }

// Evaluate the reference's chord-ECDF F at grid index k, with fp expressions
// identical to the (passing) round-3 fill: xn=-1+k*step; fm=floor; r=xn-fm;
// pos = #samples < r (seeded from the counting-sort bin table, exact);
// i=clamp(pos-1,0,510); val = fm + (y0 + slope*(r-x0)).
__device__ __forceinline__ float eval_F(const float* __restrict__ xs,
                                        const unsigned* __restrict__ prefix,
                                        int k)
{
    const float step  = (float)(3.0 / 2999.0);
    const float inv_n = 1.0f / 512.0f;
    float xn = -1.0f + (float)k * step;
    float fm = floorf(xn);
    float r  = xn - fm;                       // in [0,1)
    int b  = min((int)(r * 512.0f), NBIN - 1);
    int p  = (int)prefix[b];
    int pe = (int)prefix[b + 1];
    while (p < pe && xs[p] < r) ++p;          // exact count: #samples < r
    int i = min(max(p - 1, 0), NS - 2);
    float x0 = xs[i];
    float y0 = (float)(i + 1) * inv_n;
    float slope = inv_n * fast_rcp(xs[i + 1] - x0);
    return fm + (y0 + slope * (r - x0));
}

__global__ __launch_bounds__(256) void lcot_row_kernel(
    const float* __restrict__ x1, const float* __restrict__ x2,
    const float* __restrict__ ref, float* __restrict__ row_out)
{
    __shared__ float    s_sorted[NS];
    __shared__ unsigned s_hist[NBIN];       // histogram, then scatter cursor
    __shared__ unsigned s_prefix[NBIN + 1]; // exclusive prefix (stable)
    __shared__ float    s_wredf[4];
    __shared__ unsigned s_wredu[4];

    const int tid  = threadIdx.x;
    const int lane = tid & 63;
    const int wave = tid >> 6;
    const int row  = blockIdx.x;
    const float inv_n   = 1.0f / 512.0f;            // exact
    const float step    = (float)(3.0 / 2999.0);    // linspace(-1,2,3000) spacing
    const float invstep = 2999.0f / 3.0f;

    // preload this thread's 4 query refs once (threads 250..255 idle in inverse)
    const int j0 = tid * 4;
    float rj0 = 0.f, rj1 = 0.f, rj2 = 0.f, rj3 = 0.f;
    if (j0 < NR) {
        float4 r4 = ((const float4*)ref)[tid];
        rj0 = r4.x; rj1 = r4.y; rj2 = r4.z; rj3 = r4.w;
    }
    float e1r0 = 0.f, e1r1 = 0.f, e1r2 = 0.f, e1r3 = 0.f;   // e1 kept in registers

    float acc = 0.0f;

    for (int inp = 0; inp < 2; ++inp) {
        const float* src = (inp == 0 ? x1 : x2) + (size_t)row * NS;
        float v0 = src[tid];
        float v1 = src[tid + 256];

        // ---- zero histogram + alpha wave-partials ----
        s_hist[tid] = 0u;
        s_hist[tid + 256] = 0u;
        float s = v0 + v1;
        #pragma unroll
        for (int o = 32; o > 0; o >>= 1) s += __shfl_down(s, o, 64);
        if (lane == 0) s_wredf[wave] = s;
        __syncthreads();                                   // (A)

        // ---- histogram ----
        int b0 = min((int)(v0 * 512.0f), NBIN - 1);
        int b1 = min((int)(v1 * 512.0f), NBIN - 1);
        atomicAdd(&s_hist[b0], 1u);
        atomicAdd(&s_hist[b1], 1u);
        __syncthreads();                                   // (B)

        float alpha = (s_wredf[0] + s_wredf[1] + s_wredf[2] + s_wredf[3]) * inv_n - 0.5f;

        // ---- exclusive prefix over 512 bins (2 consecutive bins / thread) ----
        unsigned h0 = s_hist[2 * tid];
        unsigned h1 = s_hist[2 * tid + 1];
        unsigned ls = h0 + h1;
        unsigned sc0 = ls;                                 // wave inclusive scan
        #pragma unroll
        for (int o = 1; o < 64; o <<= 1) {
            unsigned t2 = __shfl_up(sc0, o, 64);
            if (lane >= o) sc0 += t2;
        }
        if (lane == 63) s_wredu[wave] = sc0;
        __syncthreads();                                   // (C)
        unsigned wbase0 = 0;
        for (int w = 0; w < 4; ++w) if (w < wave) wbase0 += s_wredu[w];
        unsigned base = wbase0 + sc0 - ls;                 // exclusive base for bin 2*tid
        s_prefix[2 * tid]     = base;
        s_prefix[2 * tid + 1] = base + h0;
        s_hist[2 * tid]       = base;                      // scatter cursors
        s_hist[2 * tid + 1]   = base + h0;
        if (tid == 255) s_prefix[NBIN] = (unsigned)NS;
        __syncthreads();                                   // (D)

        // ---- scatter ----
        unsigned p0 = atomicAdd(&s_hist[b0], 1u);
        s_sorted[p0] = v0;
        unsigned p1 = atomicAdd(&s_hist[b1], 1u);
        s_sorted[p1] = v1;
        __syncthreads();                                   // (E)

        // ---- per-bin insertion sort (exact; bins avg 1 element) ----
        for (int bb = tid; bb < NBIN; bb += 256) {
            int beg = (int)s_prefix[bb];
            int end = (int)s_prefix[bb + 1];
            for (int i2 = beg + 1; i2 < end; ++i2) {
                float key = s_sorted[i2];
                int jj = i2 - 1;
                while (jj >= beg && s_sorted[jj] > key) { s_sorted[jj + 1] = s_sorted[jj]; --jj; }
                s_sorted[jj + 1] = key;
            }
        }
        __syncthreads();                                   // (F)

        // ---- bridge values (block-uniform): the ONLY non-monotone pairs of the
        //      ecdf array are (999,1000) and (1999,2000). Queries inside a dip
        //      overlap are ambiguous under searchsorted and MUST use exact bisect.
        float t0a = eval_F(s_sorted, s_prefix, 999);
        float t0b = eval_F(s_sorted, s_prefix, 1000);
        float t1a = eval_F(s_sorted, s_prefix, 1999);
        float t1b = eval_F(s_sorted, s_prefix, 2000);

        // ---- inverse CDF at 4 contiguous queries/thread, on-demand evaluation ----
        if (j0 < NR) {
            int   k = 0;
            float F0 = 0.f, F1 = 0.f;
            bool  have = false;                // (k,F0,F1) is a valid bracket hint
            #pragma unroll
            for (int jj = 0; jj < 4; ++jj) {
                float rj = (jj == 0) ? rj0 : (jj == 1) ? rj1 : (jj == 2) ? rj2 : rj3;
                float q = rj - alpha;
                bool amb = (q > t0b && q <= t0a) || (q > t1b && q <= t1a);
                if (amb) {
                    // exact full-range bisect_left (replicates reference path on
                    // the non-monotone array, incl. which crossing it selects)
                    int lo = 0, hi = NE;
                    while (lo < hi) {
                        int mid = (lo + hi) >> 1;
                        if (eval_F(s_sorted, s_prefix, mid) < q) lo = mid + 1; else hi = mid;
                    }
                    k  = min(max(lo - 1, 0), NE - 2);
                    F0 = eval_F(s_sorted, s_prefix, k);
                    F1 = eval_F(s_sorted, s_prefix, k + 1);
                    have = false;              // bracket not guaranteed after amb
                } else {
                    if (!have) {
                        // analytic seed: invert chord structure of G (ys uniform)
                        int m = (q > t0b) + (q > t1b) - 1;
                        float u = q - (float)m;
                        int istar = min(max((int)ceilf(u * 512.0f) - 2, 0), NS - 2);
                        float xa = s_sorted[istar];
                        float xb = s_sorted[istar + 1];
                        float rstar = fmaf(u - (float)(istar + 1) * inv_n,
                                           512.0f * (xb - xa), xa);
                        float xstar = (float)m + rstar;
                        k  = min(max((int)ceilf((xstar + 1.0f) * invstep) - 1, 0), NE - 2);
                        F0 = eval_F(s_sorted, s_prefix, k);
                        F1 = eval_F(s_sorted, s_prefix, k + 1);
                    }
                    // unique crossing (q outside dip overlaps) -> local scan == bisect
                    while (k < NE - 2 && F1 < q) { ++k; F0 = F1; F1 = eval_F(s_sorted, s_prefix, k + 1); }
                    while (k > 0 && F0 >= q)     { --k; F1 = F0; F0 = eval_F(s_sorted, s_prefix, k); }
                    have = true;
                }
                float slope = step * fast_rcp(F1 - F0);
                float xn0 = -1.0f + (float)k * step;
                float res = xn0 + slope * (q - F0);
                float embv = res - rj;
                if (inp == 0) {
                    if (jj == 0) e1r0 = embv;
                    else if (jj == 1) e1r1 = embv;
                    else if (jj == 2) e1r2 = embv;
                    else e1r3 = embv;
                } else {
                    float ev = (jj == 0) ? e1r0 : (jj == 1) ? e1r1 : (jj == 2) ? e1r2 : e1r3;
                    float d = fabsf(embv - ev);
                    float c = fminf(d, 1.0f - d);
                    acc = fmaf(c, c, acc);
                }
            }
        }
        __syncthreads();                                   // (H) protect LDS before next input
    }

    // ---- block reduce acc, sqrt, write per-row ----
    #pragma unroll
    for (int o = 32; o > 0; o >>= 1) acc += __shfl_down(acc, o, 64);
    if (lane == 0) s_wredf[wave] = acc;
    __syncthreads();
    if (tid == 0) row_out[row] = sqrtf(s_wredf[0] + s_wredf[1] + s_wredf[2] + s_wredf[3]);
}

__global__ __launch_bounds__(256) void lcot_reduce_kernel(
    const float* __restrict__ row_vals, float* __restrict__ out)
{
    __shared__ float s_red[256];
    const int b = blockIdx.x;
    const int tid = threadIdx.x;
    float v = row_vals[b * NL + tid] + row_vals[b * NL + tid + 256];
    s_red[tid] = v;
    __syncthreads();
    for (int off = 128; off > 0; off >>= 1) {
        if (tid < off) s_red[tid] += s_red[tid + off];
        __syncthreads();
    }
    if (tid == 0) out[b] = s_red[0] * (1.0f / (float)NL);
}

extern "C" void kernel_launch(void* const* d_in, const int* in_sizes, int n_in,
                              void* d_out, int out_size, void* d_ws, size_t ws_size,
                              hipStream_t stream) {
    const float* x1  = (const float*)d_in[0];
    const float* x2  = (const float*)d_in[1];
    const float* ref = (const float*)d_in[2];
    float* out = (float*)d_out;
    float* row_vals = (float*)d_ws;   // NROWS floats of scratch

    lcot_row_kernel<<<NROWS, 256, 0, stream>>>(x1, x2, ref, row_vals);
    lcot_reduce_kernel<<<NB, 256, 0, stream>>>(row_vals, out);
}

// Round 8
// 191.110 us; speedup vs baseline: 1.0117x; 1.0117x over previous
//
#include <hip/hip_runtime.h>
#include <math.h>

// Problem constants (match reference)
#define NB 16       // batch
#define NL 512      // rows per batch
#define NS 512      // samples per row
#define NE 3000     // ecdf grid points (3*N_REF)
#define NR 1000     // ref points
#define NROWS (NB * NL)
#define NBIN 512    // counting-sort bins (avg 1 sample/bin)

__device__ __forceinline__ float fast_rcp(float x) { return __builtin_amdgcn_rcpf(x); }

// Evaluate the chord-ECDF F at grid index k, fp-identical to the window fill:
// xn=-1+k*step; fm=floor; r=xn-fm; pos=#samples<r (exact, from bin table);
// i=clamp(pos-1,0,510); val = fm + (y0 + slope*(r-x0)).   (round-7 verbatim)
__device__ __forceinline__ float eval_F(const float* __restrict__ xs,
                                        const unsigned* __restrict__ prefix,
                                        int k)
{
    const float step  = (float)(3.0 / 2999.0);
    const float inv_n = 1.0f / 512.0f;
    float xn = -1.0f + (float)k * step;
    float fm = floorf(xn);
    float r  = xn - fm;                       // in [0,1)
    int b  = min((int)(r * 512.0f), NBIN - 1);
    int p  = (int)prefix[b];
    int pe = (int)prefix[b + 1];
    while (p < pe && xs[p] < r) ++p;          // exact count: #samples < r
    int i = min(max(p - 1, 0), NS - 2);
    float x0 = xs[i];
    float y0 = (float)(i + 1) * inv_n;
    float slope = inv_n * fast_rcp(xs[i + 1] - x0);
    return fm + (y0 + slope * (r - x0));
}

__global__ __launch_bounds__(256) void lcot_row_kernel(
    const float* __restrict__ x1, const float* __restrict__ x2,
    const float* __restrict__ ref, float* __restrict__ row_out)
{
    __shared__ float    s_sorted[NS];
    __shared__ unsigned s_hist[NBIN];       // histogram, then scatter cursor
    __shared__ unsigned s_prefix[NBIN + 1]; // exclusive prefix (stable)
    __shared__ float    s_ecdf[NE];         // filled only on [kmin,kmax)
    __shared__ float    s_wredf[4];
    __shared__ unsigned s_wredu[4];

    const int tid  = threadIdx.x;
    const int lane = tid & 63;
    const int wave = tid >> 6;
    const int row  = blockIdx.x;
    const float inv_n   = 1.0f / 512.0f;            // exact
    const float step    = (float)(3.0 / 2999.0);    // linspace(-1,2,3000) spacing
    const float invstep = 2999.0f / 3.0f;

    // preload this thread's 4 query refs once (threads 250..255 idle in inverse)
    const int j0 = tid * 4;
    float rj0 = 0.f, rj1 = 0.f, rj2 = 0.f, rj3 = 0.f;
    if (j0 < NR) {
        float4 r4 = ((const float4*)ref)[tid];
        rj0 = r4.x; rj1 = r4.y; rj2 = r4.z; rj3 = r4.w;
    }
    float e1r0 = 0.f, e1r1 = 0.f, e1r2 = 0.f, e1r3 = 0.f;   // e1 kept in registers

    float acc = 0.0f;

    for (int inp = 0; inp < 2; ++inp) {
        const float* src = (inp == 0 ? x1 : x2) + (size_t)row * NS;
        float v0 = src[tid];
        float v1 = src[tid + 256];

        // ---- zero histogram + alpha wave-partials ----
        s_hist[tid] = 0u;
        s_hist[tid + 256] = 0u;
        float s = v0 + v1;
        #pragma unroll
        for (int o = 32; o > 0; o >>= 1) s += __shfl_down(s, o, 64);
        if (lane == 0) s_wredf[wave] = s;
        __syncthreads();                                   // (A)

        // ---- histogram ----
        int b0 = min((int)(v0 * 512.0f), NBIN - 1);
        int b1 = min((int)(v1 * 512.0f), NBIN - 1);
        atomicAdd(&s_hist[b0], 1u);
        atomicAdd(&s_hist[b1], 1u);
        __syncthreads();                                   // (B)

        float alpha = (s_wredf[0] + s_wredf[1] + s_wredf[2] + s_wredf[3]) * inv_n - 0.5f;

        // ---- exclusive prefix over 512 bins (2 consecutive bins / thread) ----
        unsigned h0 = s_hist[2 * tid];
        unsigned h1 = s_hist[2 * tid + 1];
        unsigned ls = h0 + h1;
        unsigned sc0 = ls;                                 // wave inclusive scan
        #pragma unroll
        for (int o = 1; o < 64; o <<= 1) {
            unsigned t2 = __shfl_up(sc0, o, 64);
            if (lane >= o) sc0 += t2;
        }
        if (lane == 63) s_wredu[wave] = sc0;
        __syncthreads();                                   // (C)
        unsigned wbase0 = 0;
        for (int w = 0; w < 4; ++w) if (w < wave) wbase0 += s_wredu[w];
        unsigned base = wbase0 + sc0 - ls;                 // exclusive base for bin 2*tid
        s_prefix[2 * tid]     = base;
        s_prefix[2 * tid + 1] = base + h0;
        s_hist[2 * tid]       = base;                      // scatter cursors
        s_hist[2 * tid + 1]   = base + h0;
        if (tid == 255) s_prefix[NBIN] = (unsigned)NS;
        __syncthreads();                                   // (D)

        // ---- scatter ----
        unsigned p0 = atomicAdd(&s_hist[b0], 1u);
        s_sorted[p0] = v0;
        unsigned p1 = atomicAdd(&s_hist[b1], 1u);
        s_sorted[p1] = v1;
        __syncthreads();                                   // (E)

        // ---- per-bin insertion sort (exact; bins avg 1 element) ----
        for (int bb = tid; bb < NBIN; bb += 256) {
            int beg = (int)s_prefix[bb];
            int end = (int)s_prefix[bb + 1];
            for (int i2 = beg + 1; i2 < end; ++i2) {
                float key = s_sorted[i2];
                int jj = i2 - 1;
                while (jj >= beg && s_sorted[jj] > key) { s_sorted[jj + 1] = s_sorted[jj]; --jj; }
                s_sorted[jj + 1] = key;
            }
        }
        __syncthreads();                                   // (F)

        // ---- deviation bound D = max|ECDF chord - identity| (incl. extrapolation) ----
        float dev = fmaxf(fabsf((float)(tid + 1)   * inv_n - s_sorted[tid]),
                          fabsf((float)(tid + 257) * inv_n - s_sorted[tid + 256]));
        {   // endpoint extrapolation extrema (all threads, broadcast reads)
            float sa0 = s_sorted[0], sa1 = s_sorted[1];
            float sbA = s_sorted[510], sbB = s_sorted[511];
            float sl0 = inv_n * fast_rcp(sa1 - sa0);
            float slR = inv_n * fast_rcp(sbB - sbA);
            float lext = fabsf(inv_n - sl0 * sa0);
            float rext = fabsf(511.0f * inv_n + slR * (1.0f - sbA) - 1.0f);
            dev = fmaxf(dev, fmaxf(lext, rext));
        }
        #pragma unroll
        for (int o = 32; o > 0; o >>= 1) dev = fmaxf(dev, __shfl_down(dev, o, 64));
        if (lane == 0) s_wredf[wave] = dev;
        __syncthreads();                                   // (F2)

        float Dm = fmaxf(fmaxf(s_wredf[0], s_wredf[1]), fmaxf(s_wredf[2], s_wredf[3]));
        float D  = Dm + 1.5e-3f;                           // fp slop margin (> 1 grid step)

        float qlo = 0.0f - alpha;
        float qhi = 0.999f - alpha;
        int kmin = max(0,  (int)((qlo + 1.0f - D) * invstep) - 2);
        int kmax = min(NE, (int)((qhi + 1.0f + D) * invstep) + 3);

        // ---- ECDF on window [kmin,kmax): contiguous chunk per thread, running pos ----
        {
            int W  = kmax - kmin;
            int k0 = kmin + ((tid * W) >> 8);
            int k1 = kmin + (((tid + 1) * W) >> 8);
            float fm = -100.0f;                  // force re-seed on first iter
            int pos = 0;
            int ci = -1;
            float cx0 = 0.f, cy0 = 0.f, cslope = 0.f;
            for (int k = k0; k < k1; ++k) {
                float xn  = -1.0f + (float)k * step;
                float fm2 = floorf(xn);
                float r   = xn - fm2;
                if (fm2 != fm) {
                    fm = fm2;
                    int bq  = min((int)(r * 512.0f), NBIN - 1);
                    pos     = (int)s_prefix[bq];
                    int be  = (int)s_prefix[bq + 1];
                    while (pos < be && s_sorted[pos] < r) ++pos;
                } else {
                    while (pos < NS && s_sorted[pos] < r) ++pos;
                }
                int i = min(max(pos - 1, 0), NS - 2);
                if (i != ci) {
                    ci = i;
                    cx0 = s_sorted[i];
                    cy0 = (float)(i + 1) * inv_n;
                    cslope = inv_n * fast_rcp(s_sorted[i + 1] - cx0);
                }
                s_ecdf[k] = fm + (cy0 + cslope * (r - cx0));
            }
        }
        __syncthreads();                                   // (G)

        // ---- bridge thresholds (block-uniform). The ecdf array is monotone except
        //      possibly at pairs (999,1000),(1999,2000). If a bridge pair is outside
        //      the window, no in-window query can be ambiguous there; pick +/-inf so
        //      the amb test is false and segment routing stays correct.
        float t0a, t0b, t1a, t1b;
        {
            const float inf = 3.0e38f;
            bool in0 = (kmin <= 999)  && (1000 < kmax);
            bool in1 = (kmin <= 1999) && (2000 < kmax);
            float f0 = (kmin > 999)  ? -inf : inf;
            float f1 = (kmin > 1999) ? -inf : inf;
            t0a = in0 ? s_ecdf[999]  : f0;
            t0b = in0 ? s_ecdf[1000] : f0;
            t1a = in1 ? s_ecdf[1999] : f1;
            t1b = in1 ? s_ecdf[2000] : f1;
        }

        // ---- inverse CDF: analytic seed + local scan on materialized window;
        //      ambiguous (dip-overlap) queries -> exact full-range bisect (round-7) ----
        if (j0 < NR) {
            int  k = kmin;
            bool have = false;
            #pragma unroll
            for (int jj = 0; jj < 4; ++jj) {
                float rj = (jj == 0) ? rj0 : (jj == 1) ? rj1 : (jj == 2) ? rj2 : rj3;
                float q = rj - alpha;
                float embv;
                bool amb = (q > t0b && q <= t0a) || (q > t1b && q <= t1a);
                if (amb) {
                    // exact full-range bisect_left on virtual array (reference semantics)
                    int lo = 0, hi = NE;
                    while (lo < hi) {
                        int mid = (lo + hi) >> 1;
                        if (eval_F(s_sorted, s_prefix, mid) < q) lo = mid + 1; else hi = mid;
                    }
                    int ka = min(max(lo - 1, 0), NE - 2);
                    float F0 = eval_F(s_sorted, s_prefix, ka);
                    float F1 = eval_F(s_sorted, s_prefix, ka + 1);
                    float slope = step * fast_rcp(F1 - F0);
                    float xn0 = -1.0f + (float)ka * step;
                    embv = xn0 + slope * (q - F0) - rj;
                    // carry (k,have) unchanged: last non-amb cell is still a lower bound
                } else {
                    if (!have) {
                        // analytic seed: invert chord structure of G (ys nodes uniform)
                        int m = (q > t0b) + (q > t1b) - 1;
                        float u = q - (float)m;
                        int istar = min(max((int)ceilf(u * 512.0f) - 2, 0), NS - 2);
                        float xa = s_sorted[istar];
                        float xb = s_sorted[istar + 1];
                        float rstar = fmaf(u - (float)(istar + 1) * inv_n,
                                           512.0f * (xb - xa), xa);
                        float xstar = (float)m + rstar;
                        k = min(max((int)ceilf((xstar + 1.0f) * invstep) - 1, kmin), kmax - 2);
                        have = true;
                    }
                    // unique crossing for non-amb q: local scan == bisect result
                    while (k < kmax - 2 && s_ecdf[k + 1] < q) ++k;
                    while (k > kmin && s_ecdf[k] >= q) --k;
                    float e0  = s_ecdf[k];
                    float e1v = s_ecdf[k + 1];
                    float slope = step * fast_rcp(e1v - e0);
                    float xn0 = -1.0f + (float)k * step;
                    embv = xn0 + slope * (q - e0) - rj;
                }
                if (inp == 0) {
                    if (jj == 0) e1r0 = embv;
                    else if (jj == 1) e1r1 = embv;
                    else if (jj == 2) e1r2 = embv;
                    else e1r3 = embv;
                } else {
                    float ev = (jj == 0) ? e1r0 : (jj == 1) ? e1r1 : (jj == 2) ? e1r2 : e1r3;
                    float d = fabsf(embv - ev);
                    float c = fminf(d, 1.0f - d);
                    acc = fmaf(c, c, acc);
                }
            }
        }
        __syncthreads();                                   // (H) protect LDS before next input
    }

    // ---- block reduce acc, sqrt, write per-row ----
    #pragma unroll
    for (int o = 32; o > 0; o >>= 1) acc += __shfl_down(acc, o, 64);
    if (lane == 0) s_wredf[wave] = acc;
    __syncthreads();
    if (tid == 0) row_out[row] = sqrtf(s_wredf[0] + s_wredf[1] + s_wredf[2] + s_wredf[3]);
}

__global__ __launch_bounds__(256) void lcot_reduce_kernel(
    const float* __restrict__ row_vals, float* __restrict__ out)
{
    __shared__ float s_red[256];
    const int b = blockIdx.x;
    const int tid = threadIdx.x;
    float v = row_vals[b * NL + tid] + row_vals[b * NL + tid + 256];
    s_red[tid] = v;
    __syncthreads();
    for (int off = 128; off > 0; off >>= 1) {
        if (tid < off) s_red[tid] += s_red[tid + off];
        __syncthreads();
    }
    if (tid == 0) out[b] = s_red[0] * (1.0f / (float)NL);
}

extern "C" void kernel_launch(void* const* d_in, const int* in_sizes, int n_in,
                              void* d_out, int out_size, void* d_ws, size_t ws_size,
                              hipStream_t stream) {
    const float* x1  = (const float*)d_in[0];
    const float* x2  = (const float*)d_in[1];
    const float* ref = (const float*)d_in[2];
    float* out = (float*)d_out;
    float* row_vals = (float*)d_ws;   // NROWS floats of scratch

    lcot_row_kernel<<<NROWS, 256, 0, stream>>>(x1, x2, ref, row_vals);
    lcot_reduce_kernel<<<NB, 256, 0, stream>>>(row_vals, out);
}

// Round 9
// 106.181 us; speedup vs baseline: 1.8209x; 1.7999x over previous
//
#include <hip/hip_runtime.h>
#include <math.h>

// Problem constants (match reference)
#define NB 16       // batch
#define NL 512      // rows per batch
#define NS 512      // samples per row
#define NE 3000     // ecdf grid points (3*N_REF)
#define NR 1000     // ref points
#define NROWS (NB * NL)
#define NBIN 512    // counting-sort bins (avg 1 sample/bin)

__device__ __forceinline__ float fast_rcp(float x) { return __builtin_amdgcn_rcpf(x); }

__global__ __launch_bounds__(256) void lcot_row_kernel(
    const float* __restrict__ x1, const float* __restrict__ x2,
    const float* __restrict__ ref, float* __restrict__ row_out)
{
    __shared__ float    s_sorted[NS];
    __shared__ unsigned s_hist[NBIN];       // histogram, then scatter cursor
    __shared__ unsigned s_prefix[NBIN + 1]; // exclusive prefix (stable)
    __shared__ float    s_ecdf[NE];         // filled only on [kmin,kmax)
    __shared__ float    s_alpA[4], s_alpB[4]; // alpha partials per input (written once)
    __shared__ float    s_devf[4];          // dev partials / final acc partials
    __shared__ unsigned s_wredu[4];

    const int tid  = threadIdx.x;
    const int lane = tid & 63;
    const int wave = tid >> 6;
    const int row  = blockIdx.x;
    const float inv_n   = 1.0f / 512.0f;            // exact
    const float step    = (float)(3.0 / 2999.0);    // linspace(-1,2,3000) spacing
    const float invstep = 2999.0f / 3.0f;

    // preload this thread's 4 query refs once (threads 250..255 idle in inverse)
    const int j0 = tid * 4;
    float rj0 = 0.f, rj1 = 0.f, rj2 = 0.f, rj3 = 0.f;
    if (j0 < NR) {
        float4 r4 = ((const float4*)ref)[tid];
        rj0 = r4.x; rj1 = r4.y; rj2 = r4.z; rj3 = r4.w;
    }
    float e1r0 = 0.f, e1r1 = 0.f, e1r2 = 0.f, e1r3 = 0.f;   // e1 kept in registers

    // prefetch BOTH rows up front (overlap HBM latency once)
    const float* srcA = x1 + (size_t)row * NS;
    const float* srcB = x2 + (size_t)row * NS;
    float a0 = srcA[tid], a1 = srcA[tid + 256];
    float c0 = srcB[tid], c1 = srcB[tid + 256];

    float acc = 0.0f;

    for (int inp = 0; inp < 2; ++inp) {
        float v0 = (inp == 0) ? a0 : c0;
        float v1 = (inp == 0) ? a1 : c1;

        if (inp == 0) {
            // zero histogram + BOTH inputs' alpha partial sums (once)
            s_hist[tid] = 0u;
            s_hist[tid + 256] = 0u;
            float sA = a0 + a1, sB = c0 + c1;
            #pragma unroll
            for (int o = 32; o > 0; o >>= 1) {
                sA += __shfl_down(sA, o, 64);
                sB += __shfl_down(sB, o, 64);
            }
            if (lane == 0) { s_alpA[wave] = sA; s_alpB[wave] = sB; }
            __syncthreads();                               // (A) zeroing -> atomics
        }
        // (for inp==1: hist was pre-zeroed during inp0's fill region, >=2 barriers ago)

        // ---- histogram ----
        int b0 = min((int)(v0 * 512.0f), NBIN - 1);
        int b1 = min((int)(v1 * 512.0f), NBIN - 1);
        atomicAdd(&s_hist[b0], 1u);
        atomicAdd(&s_hist[b1], 1u);
        __syncthreads();                                   // (B)

        const float* alp = (inp == 0) ? s_alpA : s_alpB;
        float alpha = (alp[0] + alp[1] + alp[2] + alp[3]) * inv_n - 0.5f;

        // ---- exclusive prefix over 512 bins (2 consecutive bins / thread) ----
        unsigned h0 = s_hist[2 * tid];
        unsigned h1 = s_hist[2 * tid + 1];
        unsigned ls = h0 + h1;
        unsigned sc0 = ls;                                 // wave inclusive scan
        #pragma unroll
        for (int o = 1; o < 64; o <<= 1) {
            unsigned t2 = __shfl_up(sc0, o, 64);
            if (lane >= o) sc0 += t2;
        }
        if (lane == 63) s_wredu[wave] = sc0;
        __syncthreads();                                   // (C)
        unsigned wbase0 = 0;
        for (int w = 0; w < 4; ++w) if (w < wave) wbase0 += s_wredu[w];
        unsigned base = wbase0 + sc0 - ls;                 // exclusive base for bin 2*tid
        s_prefix[2 * tid]     = base;
        s_prefix[2 * tid + 1] = base + h0;
        s_hist[2 * tid]       = base;                      // scatter cursors
        s_hist[2 * tid + 1]   = base + h0;
        if (tid == 255) s_prefix[NBIN] = (unsigned)NS;
        __syncthreads();                                   // (D)

        // ---- scatter + PROVISIONAL node-deviation (slot vs true rank differ by
        //      <= bin_count-1; covered by +12/512 slop on D below) ----
        unsigned p0 = atomicAdd(&s_hist[b0], 1u);
        s_sorted[p0] = v0;
        unsigned p1 = atomicAdd(&s_hist[b1], 1u);
        s_sorted[p1] = v1;
        float dv = fmaxf(fabsf((float)(p0 + 1) * inv_n - v0),
                         fabsf((float)(p1 + 1) * inv_n - v1));
        #pragma unroll
        for (int o = 32; o > 0; o >>= 1) dv = fmaxf(dv, __shfl_down(dv, o, 64));
        if (lane == 0) s_devf[wave] = dv;
        __syncthreads();                                   // (E)

        // ---- per-bin insertion sort (exact; bins avg 1 element) ----
        for (int bb = tid; bb < NBIN; bb += 256) {
            int beg = (int)s_prefix[bb];
            int end = (int)s_prefix[bb + 1];
            for (int i2 = beg + 1; i2 < end; ++i2) {
                float key = s_sorted[i2];
                int jj = i2 - 1;
                while (jj >= beg && s_sorted[jj] > key) { s_sorted[jj + 1] = s_sorted[jj]; --jj; }
                s_sorted[jj + 1] = key;
            }
        }
        __syncthreads();                                   // (F) sort + dev partials done

        // ---- deviation bound D (node partials + exact extrapolation endpoints) ----
        float Dm = fmaxf(fmaxf(s_devf[0], s_devf[1]), fmaxf(s_devf[2], s_devf[3]));
        {
            float sa0 = s_sorted[0], sa1 = s_sorted[1];
            float sbA = s_sorted[510], sbB = s_sorted[511];
            float sl0 = inv_n * fast_rcp(sa1 - sa0);
            float slR = inv_n * fast_rcp(sbB - sbA);
            float lext = fabsf(inv_n - sl0 * sa0);
            float rext = fabsf(511.0f * inv_n + slR * (1.0f - sbA) - 1.0f);
            Dm = fmaxf(Dm, fmaxf(lext, rext));
        }
        float D = Dm + 0.0249f;   // 12/512 provisional-rank slop + 1.5e-3 fp margin

        float qlo = 0.0f - alpha;
        float qhi = 0.999f - alpha;
        int kmin = max(0,  (int)((qlo + 1.0f - D) * invstep) - 2);
        int kmax = min(NE, (int)((qhi + 1.0f + D) * invstep) + 3);

        // ---- ECDF on window [kmin,kmax): contiguous chunk per thread, running pos ----
        {
            int W  = kmax - kmin;
            int k0 = kmin + ((tid * W) >> 8);
            int k1 = kmin + (((tid + 1) * W) >> 8);
            float fm = -100.0f;                  // force re-seed on first iter
            int pos = 0;
            int ci = -1;
            float cx0 = 0.f, cy0 = 0.f, cslope = 0.f;
            for (int k = k0; k < k1; ++k) {
                float xn  = -1.0f + (float)k * step;
                float fm2 = floorf(xn);
                float r   = xn - fm2;
                if (fm2 != fm) {
                    fm = fm2;
                    int bq  = min((int)(r * 512.0f), NBIN - 1);
                    pos     = (int)s_prefix[bq];
                    int be  = (int)s_prefix[bq + 1];
                    while (pos < be && s_sorted[pos] < r) ++pos;
                } else {
                    while (pos < NS && s_sorted[pos] < r) ++pos;
                }
                int i = min(max(pos - 1, 0), NS - 2);
                if (i != ci) {
                    ci = i;
                    cx0 = s_sorted[i];
                    cy0 = (float)(i + 1) * inv_n;
                    cslope = inv_n * fast_rcp(s_sorted[i + 1] - cx0);
                }
                s_ecdf[k] = fm + (cy0 + cslope * (r - cx0));
            }
        }
        // pre-zero histogram for input 2 (s_hist dead after scatter; next use is
        // inp1's atomics which are >= 2 barriers (G, then inp1-B) away)
        if (inp == 0) { s_hist[tid] = 0u; s_hist[tid + 256] = 0u; }
        __syncthreads();                                   // (G) fill done

        // ---- inverse CDF at 4 contiguous queries/thread (round-3 verbatim) ----
        if (j0 < NR) {
            float q = rj0 - alpha;
            int lo = kmin, hi = kmax;
            while (lo < hi) {                               // bisect_left (absolute idx)
                int mid = (lo + hi) >> 1;
                if (s_ecdf[mid] < q) lo = mid + 1; else hi = mid;
            }
            int pos2 = lo;
            #pragma unroll
            for (int jj = 0; jj < 4; ++jj) {
                float rj = (jj == 0) ? rj0 : (jj == 1) ? rj1 : (jj == 2) ? rj2 : rj3;
                q = rj - alpha;
                if (jj > 0) while (pos2 < NE && s_ecdf[pos2] < q) ++pos2;
                int i = min(max(pos2 - 1, 0), NE - 2);
                float e0 = s_ecdf[i];
                float slope = step * fast_rcp(s_ecdf[i + 1] - e0);
                float xn0 = -1.0f + (float)i * step;
                float res = xn0 + slope * (q - e0);
                float embv = res - rj;
                if (inp == 0) {
                    if (jj == 0) e1r0 = embv;
                    else if (jj == 1) e1r1 = embv;
                    else if (jj == 2) e1r2 = embv;
                    else e1r3 = embv;
                } else {
                    float ev = (jj == 0) ? e1r0 : (jj == 1) ? e1r1 : (jj == 2) ? e1r2 : e1r3;
                    float d = fabsf(embv - ev);
                    float c = fminf(d, 1.0f - d);
                    acc = fmaf(c, c, acc);
                }
            }
        }
        // NO end-of-input barrier needed: inp0's inverse only READS s_ecdf; inp1's
        // first write to s_ecdf is its fill, which is preceded by barriers B..F of
        // inp1 — every thread has finished its inp0 inverse before any thread can
        // reach inp1's fill. inp1's pre-B writes touch only s_hist (zeroed above,
        // read by nobody in between).
    }

    // ---- block reduce acc, sqrt, write per-row (s_devf dead, reuse) ----
    #pragma unroll
    for (int o = 32; o > 0; o >>= 1) acc += __shfl_down(acc, o, 64);
    if (lane == 0) s_devf[wave] = acc;
    __syncthreads();
    if (tid == 0) row_out[row] = sqrtf(s_devf[0] + s_devf[1] + s_devf[2] + s_devf[3]);
}

__global__ __launch_bounds__(256) void lcot_reduce_kernel(
    const float* __restrict__ row_vals, float* __restrict__ out)
{
    __shared__ float s_red[256];
    const int b = blockIdx.x;
    const int tid = threadIdx.x;
    float v = row_vals[b * NL + tid] + row_vals[b * NL + tid + 256];
    s_red[tid] = v;
    __syncthreads();
    for (int off = 128; off > 0; off >>= 1) {
        if (tid < off) s_red[tid] += s_red[tid + off];
        __syncthreads();
    }
    if (tid == 0) out[b] = s_red[0] * (1.0f / (float)NL);
}

extern "C" void kernel_launch(void* const* d_in, const int* in_sizes, int n_in,
                              void* d_out, int out_size, void* d_ws, size_t ws_size,
                              hipStream_t stream) {
    const float* x1  = (const float*)d_in[0];
    const float* x2  = (const float*)d_in[1];
    const float* ref = (const float*)d_in[2];
    float* out = (float*)d_out;
    float* row_vals = (float*)d_ws;   // NROWS floats of scratch

    lcot_row_kernel<<<NROWS, 256, 0, stream>>>(x1, x2, ref, row_vals);
    lcot_reduce_kernel<<<NB, 256, 0, stream>>>(row_vals, out);
}